// Round 2
// baseline (2652.956 us; speedup 1.0000x reference)
//
#include <hip/hip_runtime.h>
#include <cstdint>
#include <cstddef>

#define DEVI __device__ __forceinline__

DEVI float silu_f(float x) { return x / (1.f + __expf(-x)); }

// ---------------------------------------------------------------------------
// Generic fused GEMM: out[M,128] = epilogue( stage(X)[M,K] @ W[K,128] )
// STAGE: 0 = raw, 1 = LayerNorm(gamma,beta) over row (K=128 stats),
//        2 = divide by (z[row,head]+1e-6)
// BM=64 rows/block, 128 cols/launch, K chunked by 64.
// LDS: ws 32KB + xs 17KB + red 2KB = 51.2KB -> 3 blocks/CU (12 waves).
// In-place (out==X or out==resid) is safe: each block reads only its own
// 64-row tile during staging (all K-chunks) and writes it only in the
// epilogue after the last read.
// ---------------------------------------------------------------------------
template <int STAGE, bool SILU, bool BIAS, bool RESID>
__global__ __launch_bounds__(256, 3) void gemm_k(
    const float* __restrict__ X, int M, int ldx, int K,
    const float* __restrict__ W, int ldw,
    const float* __restrict__ gamma, const float* __restrict__ beta,
    const float* __restrict__ zden,
    const float* __restrict__ bias,
    const float* __restrict__ resid, int ldr,
    float* __restrict__ out, int ldo)
{
    __shared__ float ws[64 * 128];
    __shared__ float xs[64 * 68];
    __shared__ float redS[64 * 4];
    __shared__ float redQ[64 * 4];

    const int tid  = threadIdx.x;
    const int tx   = tid & 31;   // col group: 4 cols each
    const int ty   = tid >> 5;   // row group: 8 rows each
    const int rbase = blockIdx.x * 64;
    const int srow = tid >> 2;   // staging: row 0..63
    const int sq   = tid & 3;    // staging: quarter of the 64-col chunk
    const int grow = rbase + srow;
    const bool rowok = grow < M;

    float acc[8][4];
#pragma unroll
    for (int i = 0; i < 8; i++) {
        acc[i][0] = 0.f; acc[i][1] = 0.f; acc[i][2] = 0.f; acc[i][3] = 0.f;
    }

    float mu = 0.f, rstd = 0.f;  // persists across K-chunks for STAGE==1

    for (int k0 = 0; k0 < K; k0 += 64) {
        // ---- stage X chunk (64 rows x 64 cols), transposed into xs[k][row]
        float4 v[4];
#pragma unroll
        for (int i = 0; i < 4; i++) {
            int c = k0 + sq * 16 + i * 4;
            v[i] = rowok ? *(const float4*)(X + (size_t)grow * ldx + c)
                         : make_float4(0.f, 0.f, 0.f, 0.f);
        }
        if constexpr (STAGE == 1) {
            if (k0 == 0) {
                // full-row stats over 128 cols (also read cols 64..127)
                float s = 0.f, ssq = 0.f;
#pragma unroll
                for (int i = 0; i < 4; i++) {
                    s   += v[i].x + v[i].y + v[i].z + v[i].w;
                    ssq += v[i].x * v[i].x + v[i].y * v[i].y + v[i].z * v[i].z + v[i].w * v[i].w;
                }
#pragma unroll
                for (int i = 0; i < 4; i++) {
                    int c = 64 + sq * 16 + i * 4;
                    float4 u = rowok ? *(const float4*)(X + (size_t)grow * ldx + c)
                                     : make_float4(0.f, 0.f, 0.f, 0.f);
                    s   += u.x + u.y + u.z + u.w;
                    ssq += u.x * u.x + u.y * u.y + u.z * u.z + u.w * u.w;
                }
                redS[srow * 4 + sq] = s;
                redQ[srow * 4 + sq] = ssq;
                __syncthreads();
                float ts = redS[srow * 4 + 0] + redS[srow * 4 + 1] + redS[srow * 4 + 2] + redS[srow * 4 + 3];
                float tq = redQ[srow * 4 + 0] + redQ[srow * 4 + 1] + redQ[srow * 4 + 2] + redQ[srow * 4 + 3];
                mu = ts * (1.f / 128.f);
                float var = tq * (1.f / 128.f) - mu * mu;
                rstd = rsqrtf(var + 1e-5f);
            }
#pragma unroll
            for (int i = 0; i < 4; i++) {
                int c = k0 + sq * 16 + i * 4;
                float4 g4 = *(const float4*)(gamma + c);
                float4 b4 = *(const float4*)(beta + c);
                v[i].x = (v[i].x - mu) * rstd * g4.x + b4.x;
                v[i].y = (v[i].y - mu) * rstd * g4.y + b4.y;
                v[i].z = (v[i].z - mu) * rstd * g4.z + b4.z;
                v[i].w = (v[i].w - mu) * rstd * g4.w + b4.w;
            }
        } else if constexpr (STAGE == 2) {
            // divide by (z[row, head] + 1e-6); head = col/16 = (k0>>4)+sq
            int zr = rowok ? grow : 0;
            float zv = zden[(size_t)zr * 8 + (k0 >> 4) + sq];
            float rz = 1.f / (zv + 1e-6f);
#pragma unroll
            for (int i = 0; i < 4; i++) {
                v[i].x *= rz; v[i].y *= rz; v[i].z *= rz; v[i].w *= rz;
            }
        }
        // transposed write: xs[k_local][row], row-stride 68 (16B-aligned reads)
#pragma unroll
        for (int i = 0; i < 4; i++) {
            int kl = sq * 16 + i * 4;
            xs[(kl + 0) * 68 + srow] = v[i].x;
            xs[(kl + 1) * 68 + srow] = v[i].y;
            xs[(kl + 2) * 68 + srow] = v[i].z;
            xs[(kl + 3) * 68 + srow] = v[i].w;
        }
        // ---- stage W chunk (64 x 128), natural layout
#pragma unroll
        for (int it = 0; it < 8; it++) {
            int fi = it * 256 + tid;  // float4 index, 0..2047
            int kr = fi >> 5;
            int c4 = fi & 31;
            *(float4*)(ws + kr * 128 + c4 * 4) =
                *(const float4*)(W + (size_t)(k0 + kr) * ldw + c4 * 4);
        }
        __syncthreads();
        // ---- compute: 64 k-steps, 8x4 micro-tile per thread
#pragma unroll 4
        for (int k = 0; k < 64; k++) {
            float4 w4 = *(const float4*)(ws + k * 128 + tx * 4);
            float4 xa = *(const float4*)(xs + k * 68 + ty * 8);
            float4 xb = *(const float4*)(xs + k * 68 + ty * 8 + 4);
            float xr[8] = {xa.x, xa.y, xa.z, xa.w, xb.x, xb.y, xb.z, xb.w};
#pragma unroll
            for (int i = 0; i < 8; i++) {
                acc[i][0] += xr[i] * w4.x;
                acc[i][1] += xr[i] * w4.y;
                acc[i][2] += xr[i] * w4.z;
                acc[i][3] += xr[i] * w4.w;
            }
        }
        __syncthreads();
    }

    // ---- epilogue
    const int c0 = tx * 4;
    float4 b4 = make_float4(0.f, 0.f, 0.f, 0.f);
    if constexpr (BIAS) b4 = *(const float4*)(bias + c0);
#pragma unroll
    for (int i = 0; i < 8; i++) {
        int gr = rbase + ty * 8 + i;
        if (gr < M) {
            float4 o = make_float4(acc[i][0], acc[i][1], acc[i][2], acc[i][3]);
            if constexpr (BIAS) { o.x += b4.x; o.y += b4.y; o.z += b4.z; o.w += b4.w; }
            if constexpr (SILU) { o.x = silu_f(o.x); o.y = silu_f(o.y); o.z = silu_f(o.z); o.w = silu_f(o.w); }
            if constexpr (RESID) {
                float4 r4 = *(const float4*)(resid + (size_t)gr * ldr + c0);
                o.x += r4.x; o.y += r4.y; o.z += r4.z; o.w += r4.w;
            }
            *(float4*)(out + (size_t)gr * ldo + c0) = o;
        }
    }
}

// ---------------------------------------------------------------------------
// Edge attention: score = clip(K[src]*Q[dst]/4, -5,5)*PE (in-place over PE),
// w = exp(clip(sum_head(score))), atomic-accumulate w*V[src] and w into dst.
// 32 lanes per edge (4 floats/lane), 8 edges per 256-thread block.
// ---------------------------------------------------------------------------
__global__ __launch_bounds__(256) void edge_attn_k(
    const float* __restrict__ Q, const float* __restrict__ Km,
    const float* __restrict__ V, float* __restrict__ pe_score,
    const int* __restrict__ eidx, float* __restrict__ wV,
    float* __restrict__ z, int E)
{
    int e = blockIdx.x * 8 + (threadIdx.x >> 5);
    if (e >= E) return;
    int lane = threadIdx.x & 31;
    int s = eidx[e];
    int d = eidx[(size_t)E + e];
    size_t co = (size_t)lane * 4;
    float4 qv = *(const float4*)(Q + (size_t)d * 128 + co);
    float4 kv = *(const float4*)(Km + (size_t)s * 128 + co);
    float4 pe = *(const float4*)(pe_score + (size_t)e * 128 + co);
    const float sc = 0.25f;  // 1/sqrt(16)
    float4 sv;
    sv.x = fminf(fmaxf(kv.x * qv.x * sc, -5.f), 5.f) * pe.x;
    sv.y = fminf(fmaxf(kv.y * qv.y * sc, -5.f), 5.f) * pe.y;
    sv.z = fminf(fmaxf(kv.z * qv.z * sc, -5.f), 5.f) * pe.z;
    sv.w = fminf(fmaxf(kv.w * qv.w * sc, -5.f), 5.f) * pe.w;
    *(float4*)(pe_score + (size_t)e * 128 + co) = sv;
    // per-head (16 cols = 4 lanes) sum
    float hs = sv.x + sv.y + sv.z + sv.w;
    hs += __shfl_xor(hs, 1, 64);
    hs += __shfl_xor(hs, 2, 64);
    float w = __expf(fminf(fmaxf(hs, -5.f), 5.f));
    float4 vv = *(const float4*)(V + (size_t)s * 128 + co);
    unsafeAtomicAdd(&wV[(size_t)d * 128 + co + 0], w * vv.x);
    unsafeAtomicAdd(&wV[(size_t)d * 128 + co + 1], w * vv.y);
    unsafeAtomicAdd(&wV[(size_t)d * 128 + co + 2], w * vv.z);
    unsafeAtomicAdd(&wV[(size_t)d * 128 + co + 3], w * vv.w);
    if ((lane & 3) == 0) unsafeAtomicAdd(&z[(size_t)d * 8 + (lane >> 2)], w);
}

// ---------------------------------------------------------------------------
extern "C" void kernel_launch(void* const* d_in, const int* in_sizes, int n_in,
                              void* d_out, int out_size, void* d_ws, size_t ws_size,
                              hipStream_t stream)
{
    const float* node  = (const float*)d_in[0];
    const float* edgef = (const float*)d_in[1];
    const int*   eidx  = (const int*)d_in[2];
    const float* Wq = (const float*)d_in[3];
    const float* Wk = (const float*)d_in[4];
    const float* Wv = (const float*)d_in[5];
    const float* We = (const float*)d_in[6];
    const float* Wo_n = (const float*)d_in[7];
    const float* bo_n = (const float*)d_in[8];
    const float* Wo_e = (const float*)d_in[9];
    const float* bo_e = (const float*)d_in[10];
    const float* W1n = (const float*)d_in[11];
    const float* W2n = (const float*)d_in[12];
    const float* W1e = (const float*)d_in[13];
    const float* W2e = (const float*)d_in[14];
    const float* g1n = (const float*)d_in[15];
    const float* b1n = (const float*)d_in[16];
    const float* g1e = (const float*)d_in[17];
    const float* b1e = (const float*)d_in[18];
    const float* g2n = (const float*)d_in[19];
    const float* b2n = (const float*)d_in[20];
    const float* g2e = (const float*)d_in[21];
    const float* b2e = (const float*)d_in[22];

    const int N = in_sizes[0] / 128;
    const int E = in_sizes[1] / 128;
    float* outn = (float*)d_out;                    // node region: also h2 buffer
    float* oute = (float*)d_out + (size_t)N * 128;  // edge region: PE->score->e2->e_out chain

    // ---- workspace layout (fits in ~104 MB + adaptive tb) ----
    float* p = (float*)d_ws;
    float* Qb = p; p += (size_t)N * 128;
    float* Kb = p; p += (size_t)N * 128;
    float* Vb = p; p += (size_t)N * 128;
    float* wV = p; p += (size_t)N * 128;
    float* zb = p; p += (size_t)N * 8;
    float* tb = p;
    // adaptive FFN row-chunk so tb = chunk*256 floats fits in remaining ws
    size_t used = (size_t)(p - (float*)d_ws);
    size_t total = ws_size / sizeof(float);
    size_t avail = (total > used) ? (total - used) : 0;
    long long chunk = (long long)(avail / 256);
    if (chunk > 60000) chunk = 60000;   // 60k rows = 61 MB temp, 938 blocks/launch
    if (chunk < 1024)  chunk = 1024;    // last-resort floor

    hipMemsetAsync(wV, 0, (size_t)N * 128 * sizeof(float), stream);
    hipMemsetAsync(zb, 0, (size_t)N * 8 * sizeof(float), stream);

    const int rbN = (N + 63) / 64;
    const int rbE = (E + 63) / 64;
    dim3 blk(256);

    // 1) Q/K/V = LN1(node) @ {Wq,Wk,Wv}
    gemm_k<1, false, false, false><<<rbN, blk, 0, stream>>>(
        node, N, 128, 128, Wq, 128, g1n, b1n, nullptr, nullptr, nullptr, 0, Qb, 128);
    gemm_k<1, false, false, false><<<rbN, blk, 0, stream>>>(
        node, N, 128, 128, Wk, 128, g1n, b1n, nullptr, nullptr, nullptr, 0, Kb, 128);
    gemm_k<1, false, false, false><<<rbN, blk, 0, stream>>>(
        node, N, 128, 128, Wv, 128, g1n, b1n, nullptr, nullptr, nullptr, 0, Vb, 128);

    // 2) PE = LN1(edge) @ We  -> oute (d_out edge region as scratch)
    gemm_k<1, false, false, false><<<rbE, blk, 0, stream>>>(
        edgef, E, 128, 128, We, 128, g1e, b1e, nullptr, nullptr, nullptr, 0, oute, 128);

    // 3) edge attention: score in-place over oute; atomic wV/z aggregation
    edge_attn_k<<<(E + 7) / 8, blk, 0, stream>>>(Qb, Kb, Vb, oute, eidx, wV, zb, E);

    // 4) h2 = node + (wV/(z+1e-6)) @ Wo_n + bo_n   -> outn
    gemm_k<2, false, true, true><<<rbN, blk, 0, stream>>>(
        wV, N, 128, 128, Wo_n, 128, nullptr, nullptr, zb, bo_n, node, 128, outn, 128);

    // 5) e2 = edge + score @ Wo_e + bo_e   (in-place on oute)
    gemm_k<0, false, true, true><<<rbE, blk, 0, stream>>>(
        oute, E, 128, 128, Wo_e, 128, nullptr, nullptr, nullptr, bo_e, edgef, 128, oute, 128);

    // 6) node FFN (chunked, in-place on outn):
    //    outn = h2 + silu(LN2(h2) @ W1n) @ W2n
    for (long long b = 0; b < N; b += chunk) {
        const int Mc = (int)(((long long)N - b < chunk) ? (N - b) : chunk);
        const int rb = (Mc + 63) / 64;
        const float* xc = outn + (size_t)b * 128;
        gemm_k<1, true, false, false><<<rb, blk, 0, stream>>>(
            xc, Mc, 128, 128, W1n, 256, g2n, b2n, nullptr, nullptr, nullptr, 0, tb, 256);
        gemm_k<1, true, false, false><<<rb, blk, 0, stream>>>(
            xc, Mc, 128, 128, W1n + 128, 256, g2n, b2n, nullptr, nullptr, nullptr, 0, tb + 128, 256);
        gemm_k<0, false, false, true><<<rb, blk, 0, stream>>>(
            tb, Mc, 256, 256, W2n, 128, nullptr, nullptr, nullptr, nullptr, xc, 128,
            outn + (size_t)b * 128, 128);
    }

    // 7) edge FFN (chunked, in-place on oute):
    //    oute = e2 + silu(LN2(e2) @ W1e) @ W2e
    for (long long b = 0; b < E; b += chunk) {
        const int Mc = (int)(((long long)E - b < chunk) ? (E - b) : chunk);
        const int rb = (Mc + 63) / 64;
        const float* xc = oute + (size_t)b * 128;
        gemm_k<1, true, false, false><<<rb, blk, 0, stream>>>(
            xc, Mc, 128, 128, W1e, 256, g2e, b2e, nullptr, nullptr, nullptr, 0, tb, 256);
        gemm_k<1, true, false, false><<<rb, blk, 0, stream>>>(
            xc, Mc, 128, 128, W1e + 128, 256, g2e, b2e, nullptr, nullptr, nullptr, 0, tb + 128, 256);
        gemm_k<0, false, false, true><<<rb, blk, 0, stream>>>(
            tb, Mc, 256, 256, W2e, 128, nullptr, nullptr, nullptr, nullptr, xc, 128,
            oute + (size_t)b * 128, 128);
    }
}

// Round 3
// 2253.770 us; speedup vs baseline: 1.1771x; 1.1771x over previous
//
#include <hip/hip_runtime.h>
#include <cstdint>
#include <cstddef>

#define DEVI __device__ __forceinline__

typedef __attribute__((ext_vector_type(8))) short short8;   // 8 bf16 = 4 VGPRs
typedef __attribute__((ext_vector_type(4))) float float4v;  // MFMA acc

DEVI float silu_f(float x) { return x / (1.f + __expf(-x)); }

DEVI unsigned short f2bf(float f) {
    union { float f; unsigned u; } x{f};
    unsigned r = x.u + 0x7FFF + ((x.u >> 16) & 1);  // RNE
    return (unsigned short)(r >> 16);
}
DEVI unsigned pack2(float a, float b) {
    return (unsigned)f2bf(a) | ((unsigned)f2bf(b) << 16);
}

// ---------------------------------------------------------------------------
// Weight pre-convert: src[K][N] fp32 -> dst[N][K] bf16 (transposed), 10 mats.
// ---------------------------------------------------------------------------
struct WDesc { const float* src; unsigned short* dst; int K; int N; };
struct WPack { WDesc d[10]; };

__global__ __launch_bounds__(256) void cvt_all_k(WPack p) {
    const WDesc w = p.d[blockIdx.y];
    const int total = w.K * w.N;
    const int ln = (w.N == 256) ? 8 : 7;  // N is 128 or 256
    const int nm = w.N - 1;
    for (int idx = blockIdx.x * 256 + threadIdx.x; idx < total; idx += gridDim.x * 256) {
        int k = idx >> ln, n = idx & nm;
        w.dst[(size_t)n * w.K + k] = f2bf(w.src[idx]);
    }
}

// ---------------------------------------------------------------------------
// bf16 MFMA GEMM: out[M,128] = epi( stage(X)[M,K] @ W[K,128] )
// WT is pre-transposed bf16: WT[n][k], ldwt = K.
// STAGE: 0 raw, 1 LayerNorm over K=128 row, 2 divide by (z[row,head]+1e-6)
// Block 256 thr = 4 waves; tile M=128 x N=128, BK=64 (2 MFMA k-steps).
// Wave w: rows [w*32, w*32+32) x all 128 cols -> 2x8 MFMA tiles, 64 acc VGPRs.
// LDS: A 128x72 bf16 + B 128x72 bf16 + red 2KB = 38.9 KB.
// In-place safe: block reads only its own 128-row tile, writes in epilogue.
// ---------------------------------------------------------------------------
template <int STAGE, bool SILU, bool BIAS, bool RESID>
__global__ __launch_bounds__(256, 2) void mgemm_k(
    const float* __restrict__ X, int M, int ldx, int K,
    const short* __restrict__ WT,
    const float* __restrict__ gamma, const float* __restrict__ beta,
    const float* __restrict__ zden,
    const float* __restrict__ bias,
    const float* __restrict__ resid, int ldr,
    float* __restrict__ out, int ldo)
{
    __shared__ short Als[128 * 72];
    __shared__ short Bls[128 * 72];
    __shared__ float redS[256];
    __shared__ float redQ[256];

    const int tid  = threadIdx.x;
    const int l    = tid & 63;
    const int w    = tid >> 6;
    const int lanem = l & 15;
    const int laneq = l >> 4;         // quad 0..3
    const int rbase = blockIdx.x * 128;

    // staging role: row sm (0..127), k-half h (0..1)
    const int sm = tid >> 1;
    const int h  = tid & 1;
    const int grow = rbase + sm;
    const bool rowok = grow < M;

    float4v acc[2][8];
#pragma unroll
    for (int mt = 0; mt < 2; mt++)
#pragma unroll
        for (int nt = 0; nt < 8; nt++)
            acc[mt][nt] = (float4v){0.f, 0.f, 0.f, 0.f};

    float mu = 0.f, rstd = 0.f;
    if constexpr (STAGE == 1) {
        // full-row stats pre-pass (K==128 for all STAGE1 uses)
        float s = 0.f, q = 0.f;
        const float* xr = X + (size_t)grow * ldx + h * 64;
#pragma unroll
        for (int i = 0; i < 16; i++) {
            float4 v = rowok ? *(const float4*)(xr + i * 4) : make_float4(0.f, 0.f, 0.f, 0.f);
            s += v.x + v.y + v.z + v.w;
            q += v.x * v.x + v.y * v.y + v.z * v.z + v.w * v.w;
        }
        redS[tid] = s; redQ[tid] = q;
        __syncthreads();
        float ts = redS[sm * 2] + redS[sm * 2 + 1];
        float tq = redQ[sm * 2] + redQ[sm * 2 + 1];
        mu = ts * (1.f / 128.f);
        float var = tq * (1.f / 128.f) - mu * mu;
        rstd = rsqrtf(var + 1e-5f);
    }

    for (int k0 = 0; k0 < K; k0 += 64) {
        const int kb = k0 + h * 32;
        // ---- stage A: 32 fp32 -> 32 bf16 into Als[sm][kb..kb+31]
        float4 v[8];
        {
            const float* xr = X + (size_t)grow * ldx + kb;
#pragma unroll
            for (int i = 0; i < 8; i++)
                v[i] = rowok ? *(const float4*)(xr + i * 4) : make_float4(0.f, 0.f, 0.f, 0.f);
        }
        if constexpr (STAGE == 1) {
#pragma unroll
            for (int i = 0; i < 8; i++) {
                int c = kb + i * 4;
                float4 g4 = *(const float4*)(gamma + c);
                float4 b4 = *(const float4*)(beta + c);
                v[i].x = (v[i].x - mu) * rstd * g4.x + b4.x;
                v[i].y = (v[i].y - mu) * rstd * g4.y + b4.y;
                v[i].z = (v[i].z - mu) * rstd * g4.z + b4.z;
                v[i].w = (v[i].w - mu) * rstd * g4.w + b4.w;
            }
        } else if constexpr (STAGE == 2) {
            int zr = rowok ? grow : 0;
            float rza = 1.f / (zden[(size_t)zr * 8 + (kb >> 4)] + 1e-6f);
            float rzb = 1.f / (zden[(size_t)zr * 8 + (kb >> 4) + 1] + 1e-6f);
#pragma unroll
            for (int i = 0; i < 8; i++) {
                float rz = (i < 4) ? rza : rzb;
                v[i].x *= rz; v[i].y *= rz; v[i].z *= rz; v[i].w *= rz;
            }
        }
        {
            uint4* ad = (uint4*)(Als + sm * 72 + h * 32);
#pragma unroll
            for (int i = 0; i < 4; i++) {
                uint4 o;
                o.x = pack2(v[i * 2].x, v[i * 2].y);
                o.y = pack2(v[i * 2].z, v[i * 2].w);
                o.z = pack2(v[i * 2 + 1].x, v[i * 2 + 1].y);
                o.w = pack2(v[i * 2 + 1].z, v[i * 2 + 1].w);
                ad[i] = o;
            }
        }
        // ---- stage B: WT row sm (=out col), 32 bf16 direct copy
        {
            const uint4* bs = (const uint4*)(WT + (size_t)sm * K + kb);
            uint4* bd = (uint4*)(Bls + sm * 72 + h * 32);
#pragma unroll
            for (int i = 0; i < 4; i++) bd[i] = bs[i];
        }
        __syncthreads();
        // ---- compute: 2 k-steps of 32
#pragma unroll
        for (int s = 0; s < 2; s++) {
            const int ko = s * 32 + laneq * 8;
            short8 bfr[8];
#pragma unroll
            for (int nt = 0; nt < 8; nt++)
                bfr[nt] = *(const short8*)(Bls + (nt * 16 + lanem) * 72 + ko);
#pragma unroll
            for (int mt = 0; mt < 2; mt++) {
                short8 af = *(const short8*)(Als + (w * 32 + mt * 16 + lanem) * 72 + ko);
#pragma unroll
                for (int nt = 0; nt < 8; nt++)
                    acc[mt][nt] = __builtin_amdgcn_mfma_f32_16x16x32_bf16(
                        af, bfr[nt], acc[mt][nt], 0, 0, 0);
            }
        }
        __syncthreads();
    }

    // ---- epilogue: D[row=quad*4+reg][col=lanem] per (mt,nt)
#pragma unroll
    for (int mt = 0; mt < 2; mt++) {
#pragma unroll
        for (int nt = 0; nt < 8; nt++) {
            const int gc = nt * 16 + lanem;
            float bv = 0.f;
            if constexpr (BIAS) bv = bias[gc];
            float4v d = acc[mt][nt];
#pragma unroll
            for (int r = 0; r < 4; r++) {
                int gr = rbase + w * 32 + mt * 16 + laneq * 4 + r;
                if (gr < M) {
                    float o = d[r] + bv;
                    if constexpr (SILU) o = silu_f(o);
                    if constexpr (RESID) o += resid[(size_t)gr * ldr + gc];
                    out[(size_t)gr * ldo + gc] = o;
                }
            }
        }
    }
}

// ---------------------------------------------------------------------------
// Edge attention: score = clip(K[src]*Q[dst]/4,-5,5)*PE (in-place over PE),
// w = exp(clip(head-sum)), atomic wV/z into dst. 32 lanes/edge.
// ---------------------------------------------------------------------------
__global__ __launch_bounds__(256) void edge_attn_k(
    const float* __restrict__ Q, const float* __restrict__ Km,
    const float* __restrict__ V, float* __restrict__ pe_score,
    const int* __restrict__ eidx, float* __restrict__ wV,
    float* __restrict__ z, int E)
{
    int e = blockIdx.x * 8 + (threadIdx.x >> 5);
    if (e >= E) return;
    int lane = threadIdx.x & 31;
    int s = eidx[e];
    int d = eidx[(size_t)E + e];
    size_t co = (size_t)lane * 4;
    float4 qv = *(const float4*)(Q + (size_t)d * 128 + co);
    float4 kv = *(const float4*)(Km + (size_t)s * 128 + co);
    float4 pe = *(const float4*)(pe_score + (size_t)e * 128 + co);
    const float sc = 0.25f;  // 1/sqrt(16)
    float4 sv;
    sv.x = fminf(fmaxf(kv.x * qv.x * sc, -5.f), 5.f) * pe.x;
    sv.y = fminf(fmaxf(kv.y * qv.y * sc, -5.f), 5.f) * pe.y;
    sv.z = fminf(fmaxf(kv.z * qv.z * sc, -5.f), 5.f) * pe.z;
    sv.w = fminf(fmaxf(kv.w * qv.w * sc, -5.f), 5.f) * pe.w;
    *(float4*)(pe_score + (size_t)e * 128 + co) = sv;
    float hs = sv.x + sv.y + sv.z + sv.w;
    hs += __shfl_xor(hs, 1, 64);
    hs += __shfl_xor(hs, 2, 64);
    float w = __expf(fminf(fmaxf(hs, -5.f), 5.f));
    float4 vv = *(const float4*)(V + (size_t)s * 128 + co);
    unsafeAtomicAdd(&wV[(size_t)d * 128 + co + 0], w * vv.x);
    unsafeAtomicAdd(&wV[(size_t)d * 128 + co + 1], w * vv.y);
    unsafeAtomicAdd(&wV[(size_t)d * 128 + co + 2], w * vv.z);
    unsafeAtomicAdd(&wV[(size_t)d * 128 + co + 3], w * vv.w);
    if ((lane & 3) == 0) unsafeAtomicAdd(&z[(size_t)d * 8 + (lane >> 2)], w);
}

// ---------------------------------------------------------------------------
extern "C" void kernel_launch(void* const* d_in, const int* in_sizes, int n_in,
                              void* d_out, int out_size, void* d_ws, size_t ws_size,
                              hipStream_t stream)
{
    const float* node  = (const float*)d_in[0];
    const float* edgef = (const float*)d_in[1];
    const int*   eidx  = (const int*)d_in[2];
    const float* Wq = (const float*)d_in[3];
    const float* Wk = (const float*)d_in[4];
    const float* Wv = (const float*)d_in[5];
    const float* We = (const float*)d_in[6];
    const float* Wo_n = (const float*)d_in[7];
    const float* bo_n = (const float*)d_in[8];
    const float* Wo_e = (const float*)d_in[9];
    const float* bo_e = (const float*)d_in[10];
    const float* W1n = (const float*)d_in[11];
    const float* W2n = (const float*)d_in[12];
    const float* W1e = (const float*)d_in[13];
    const float* W2e = (const float*)d_in[14];
    const float* g1n = (const float*)d_in[15];
    const float* b1n = (const float*)d_in[16];
    const float* g1e = (const float*)d_in[17];
    const float* b1e = (const float*)d_in[18];
    const float* g2n = (const float*)d_in[19];
    const float* b2n = (const float*)d_in[20];
    const float* g2e = (const float*)d_in[21];
    const float* b2e = (const float*)d_in[22];

    const int N = in_sizes[0] / 128;
    const int E = in_sizes[1] / 128;
    float* outn = (float*)d_out;                    // node region (doubles as h2)
    float* oute = (float*)d_out + (size_t)N * 128;  // edge region: PE->score->e2->e_out

    // ---- workspace: bf16 transposed weights first, then fp32 buffers ----
    unsigned short* wts = (unsigned short*)d_ws;
    unsigned short* WqT  = wts;            // 128x128
    unsigned short* WkT  = wts + 16384;
    unsigned short* WvT  = wts + 32768;
    unsigned short* WeT  = wts + 49152;
    unsigned short* WonT = wts + 65536;
    unsigned short* WoeT = wts + 81920;
    unsigned short* W1nT = wts + 98304;    // 256x128
    unsigned short* W1eT = wts + 131072;   // 256x128
    unsigned short* W2nT = wts + 163840;   // 128x256
    unsigned short* W2eT = wts + 196608;   // 128x256  (end: 229376 shorts)
    float* p = (float*)(wts + 229376);
    float* Qb = p; p += (size_t)N * 128;
    float* Kb = p; p += (size_t)N * 128;
    float* Vb = p; p += (size_t)N * 128;
    float* wV = p; p += (size_t)N * 128;
    float* zb = p; p += (size_t)N * 8;
    float* tb = p;
    size_t used = (size_t)((char*)p - (char*)d_ws) / 4;
    size_t total = ws_size / sizeof(float);
    size_t avail = (total > used) ? (total - used) : 0;
    long long chunk = (long long)(avail / 256);
    if (chunk > 60032) chunk = 60032;
    if (chunk < 1024)  chunk = 1024;
    chunk &= ~127LL;

    // ---- weight conversion (one launch, 10 matrices) ----
    {
        WPack pk;
        pk.d[0] = {Wq,   WqT,  128, 128}; pk.d[1] = {Wk,   WkT,  128, 128};
        pk.d[2] = {Wv,   WvT,  128, 128}; pk.d[3] = {We,   WeT,  128, 128};
        pk.d[4] = {Wo_n, WonT, 128, 128}; pk.d[5] = {Wo_e, WoeT, 128, 128};
        pk.d[6] = {W1n,  W1nT, 128, 256}; pk.d[7] = {W1e,  W1eT, 128, 256};
        pk.d[8] = {W2n,  W2nT, 256, 128}; pk.d[9] = {W2e,  W2eT, 256, 128};
        cvt_all_k<<<dim3(128, 10), 256, 0, stream>>>(pk);
    }

    hipMemsetAsync(wV, 0, (size_t)N * 128 * sizeof(float), stream);
    hipMemsetAsync(zb, 0, (size_t)N * 8 * sizeof(float), stream);

    const int rbN = (N + 127) / 128;
    const int rbE = (E + 127) / 128;
    dim3 blk(256);

    // 1) Q/K/V = LN1(node) @ {Wq,Wk,Wv}
    mgemm_k<1, false, false, false><<<rbN, blk, 0, stream>>>(
        node, N, 128, 128, (const short*)WqT, g1n, b1n, nullptr, nullptr, nullptr, 0, Qb, 128);
    mgemm_k<1, false, false, false><<<rbN, blk, 0, stream>>>(
        node, N, 128, 128, (const short*)WkT, g1n, b1n, nullptr, nullptr, nullptr, 0, Kb, 128);
    mgemm_k<1, false, false, false><<<rbN, blk, 0, stream>>>(
        node, N, 128, 128, (const short*)WvT, g1n, b1n, nullptr, nullptr, nullptr, 0, Vb, 128);

    // 2) PE = LN1(edge) @ We -> oute
    mgemm_k<1, false, false, false><<<rbE, blk, 0, stream>>>(
        edgef, E, 128, 128, (const short*)WeT, g1e, b1e, nullptr, nullptr, nullptr, 0, oute, 128);

    // 3) edge attention (score in-place over oute; wV/z atomics)
    edge_attn_k<<<(E + 7) / 8, blk, 0, stream>>>(Qb, Kb, Vb, oute, eidx, wV, zb, E);

    // 4) h2 = node + (wV/(z+1e-6)) @ Wo_n + bo_n -> outn
    mgemm_k<2, false, true, true><<<rbN, blk, 0, stream>>>(
        wV, N, 128, 128, (const short*)WonT, nullptr, nullptr, zb, bo_n, node, 128, outn, 128);

    // 5) e2 = edge + score @ Wo_e + bo_e (in-place on oute)
    mgemm_k<0, false, true, true><<<rbE, blk, 0, stream>>>(
        oute, E, 128, 128, (const short*)WoeT, nullptr, nullptr, nullptr, bo_e, edgef, 128, oute, 128);

    // 6) node FFN (chunked, in-place on outn)
    for (long long b = 0; b < N; b += chunk) {
        const int Mc = (int)(((long long)N - b < chunk) ? (N - b) : chunk);
        const int rb = (Mc + 127) / 128;
        float* xc = outn + (size_t)b * 128;
        mgemm_k<1, true, false, false><<<rb, blk, 0, stream>>>(
            xc, Mc, 128, 128, (const short*)W1nT, g2n, b2n, nullptr, nullptr, nullptr, 0, tb, 256);
        mgemm_k<1, true, false, false><<<rb, blk, 0, stream>>>(
            xc, Mc, 128, 128, (const short*)(W1nT + 128 * 128), g2n, b2n, nullptr, nullptr, nullptr, 0, tb + 128, 256);
        mgemm_k<0, false, false, true><<<rb, blk, 0, stream>>>(
            tb, Mc, 256, 256, (const short*)W2nT, nullptr, nullptr, nullptr, nullptr, xc, 128, xc, 128);
    }

    // 7) edge FFN (chunked, in-place on oute)
    for (long long b = 0; b < E; b += chunk) {
        const int Mc = (int)(((long long)E - b < chunk) ? (E - b) : chunk);
        const int rb = (Mc + 127) / 128;
        float* xc = oute + (size_t)b * 128;
        mgemm_k<1, true, false, false><<<rb, blk, 0, stream>>>(
            xc, Mc, 128, 128, (const short*)W1eT, g2e, b2e, nullptr, nullptr, nullptr, 0, tb, 256);
        mgemm_k<1, true, false, false><<<rb, blk, 0, stream>>>(
            xc, Mc, 128, 128, (const short*)(W1eT + 128 * 128), g2e, b2e, nullptr, nullptr, nullptr, 0, tb + 128, 256);
        mgemm_k<0, false, false, true><<<rb, blk, 0, stream>>>(
            tb, Mc, 256, 256, (const short*)W2eT, nullptr, nullptr, nullptr, nullptr, xc, 128, xc, 128);
    }
}